// Round 8
// baseline (560.666 us; speedup 1.0000x reference)
//
#include <hip/hip_runtime.h>
#include <cstdint>
#include <cstddef>

#define N_USERS   100000
#define N_NODES   500000
#define DIM       64
#define N_EDGES   2000000
#define BATCH     4096
#define SCAN_B    1024
#define NBLK      ((N_NODES + SCAN_B - 1) / SCAN_B)   // 489
#define NMASKW    ((N_NODES + 31) / 32)               // 15625 words
#define NPACK     ((N_NODES + 3) / 4)                 // packed byte counters
#define X1C_CAP   350000   // |fB| ~230k measured-safe
#define LA_CAP    150000   // |fA| ~60k expected

typedef unsigned char uchar;
typedef unsigned short ushort;
typedef unsigned int uint;

__device__ __forceinline__ ushort f2bf(float f) {
    uint u = __float_as_uint(f);
    uint r = u + 0x7FFFu + ((u >> 16) & 1u);
    return (ushort)(r >> 16);
}
__device__ __forceinline__ float bflo(uint u) { return __uint_as_float(u << 16); }
__device__ __forceinline__ float bfhi(uint u) { return __uint_as_float(u & 0xFFFF0000u); }

__device__ __forceinline__ int getbit(const uint* __restrict__ w, int i) {
    return (w[i >> 5] >> (i & 31)) & 1;
}
__device__ __forceinline__ void setbit(uint* w, int i) {
    uint m = 1u << (i & 31);
    if (!(w[i >> 5] & m)) atomicOr(&w[i >> 5], m);
}

// ---------- mark batch indices into three bitmasks --------------------------
__global__ void k_mark(const int* __restrict__ u, const int* __restrict__ p,
                       const int* __restrict__ n, uint* __restrict__ f3w,
                       uint* __restrict__ fAw, uint* __restrict__ fBw) {
    int i = blockIdx.x * blockDim.x + threadIdx.x;
    if (i >= 3 * BATCH) return;
    int idx;
    if (i < BATCH)          idx = u[i];
    else if (i < 2 * BATCH) idx = p[i - BATCH];
    else                    idx = n[i - 2 * BATCH];
    atomicOr(&f3w[idx >> 5], 1u << (idx & 31));
    atomicOr(&fAw[idx >> 5], 1u << (idx & 31));
    atomicOr(&fBw[idx >> 5], 1u << (idx & 31));
}

// ---------- fused: packed-byte degree histogram + expand f3 -> fA -----------
__global__ void k_degexp(const int* __restrict__ src, const int* __restrict__ dst,
                         uint* __restrict__ degP, const uint* __restrict__ f3w,
                         uint* __restrict__ fAw) {
    int t = blockIdx.x * blockDim.x + threadIdx.x;
    if (t < N_EDGES / 4) {
        int4 s = ((const int4*)src)[t];
        int4 d = ((const int4*)dst)[t];
        atomicAdd(&degP[d.x >> 2], 1u << ((d.x & 3) * 8));
        atomicAdd(&degP[d.y >> 2], 1u << ((d.y & 3) * 8));
        atomicAdd(&degP[d.z >> 2], 1u << ((d.z & 3) * 8));
        atomicAdd(&degP[d.w >> 2], 1u << ((d.w & 3) * 8));
        if (getbit(f3w, d.x)) setbit(fAw, s.x);
        if (getbit(f3w, d.y)) setbit(fAw, s.y);
        if (getbit(f3w, d.z)) setbit(fAw, s.z);
        if (getbit(f3w, d.w)) setbit(fAw, s.w);
    }
}

// ---------- expand fA -> fB (bitmask, dedup) --------------------------------
__global__ void k_expand(const int* __restrict__ src, const int* __restrict__ dst,
                         const uint* __restrict__ fAw, uint* __restrict__ fBw) {
    int t = blockIdx.x * blockDim.x + threadIdx.x;
    if (t < N_EDGES / 4) {
        int4 s = ((const int4*)src)[t];
        int4 d = ((const int4*)dst)[t];
        if (getbit(fAw, d.x)) setbit(fBw, s.x);
        if (getbit(fAw, d.y)) setbit(fBw, s.y);
        if (getbit(fAw, d.z)) setbit(fBw, s.z);
        if (getbit(fAw, d.w)) setbit(fBw, s.w);
    }
}

// ---------- scan A: per-block sums of deg (packed) and fA|fB (bits) ---------
__global__ void k_scanA(const uint* __restrict__ degP, const uint* __restrict__ fAw,
                        const uint* __restrict__ fBw, int* __restrict__ bsumD,
                        int* __restrict__ bsumP) {
    __shared__ int sD[SCAN_B];
    __shared__ int sP[SCAN_B];
    int i = blockIdx.x * SCAN_B + threadIdx.x;
    int d = 0, pk = 0;
    if (i < N_NODES) {
        d = (degP[i >> 2] >> ((i & 3) * 8)) & 0xFF;
        pk = getbit(fAw, i) | (getbit(fBw, i) << 16);
    }
    sD[threadIdx.x] = d; sP[threadIdx.x] = pk;
    __syncthreads();
    for (int off = SCAN_B / 2; off; off >>= 1) {
        if (threadIdx.x < off) {
            sD[threadIdx.x] += sD[threadIdx.x + off];
            sP[threadIdx.x] += sP[threadIdx.x + off];
        }
        __syncthreads();
    }
    if (threadIdx.x == 0) { bsumD[blockIdx.x] = sD[0]; bsumP[blockIdx.x] = sP[0]; }
}

// ---------- scan B: exclusive scans of block sums ---------------------------
__global__ void k_scanB(const int* __restrict__ bsumD, const int* __restrict__ bsumP,
                        int* __restrict__ boffD, int* __restrict__ boffA,
                        int* __restrict__ boffB, int* __restrict__ counts,
                        int* __restrict__ rowstart_tail) {
    __shared__ int sD[512];
    __shared__ int sA[512];
    __shared__ int sB[512];
    int d = (threadIdx.x < NBLK) ? bsumD[threadIdx.x] : 0;
    int p = (threadIdx.x < NBLK) ? bsumP[threadIdx.x] : 0;
    int a = p & 0xFFFF, b = p >> 16;
    sD[threadIdx.x] = d; sA[threadIdx.x] = a; sB[threadIdx.x] = b;
    __syncthreads();
    for (int off = 1; off < 512; off <<= 1) {
        int tD = (threadIdx.x >= off) ? sD[threadIdx.x - off] : 0;
        int tA = (threadIdx.x >= off) ? sA[threadIdx.x - off] : 0;
        int tB = (threadIdx.x >= off) ? sB[threadIdx.x - off] : 0;
        __syncthreads();
        sD[threadIdx.x] += tD; sA[threadIdx.x] += tA; sB[threadIdx.x] += tB;
        __syncthreads();
    }
    if (threadIdx.x < NBLK) {
        boffD[threadIdx.x] = sD[threadIdx.x] - d;
        boffA[threadIdx.x] = sA[threadIdx.x] - a;
        boffB[threadIdx.x] = sB[threadIdx.x] - b;
    }
    if (threadIdx.x == 511) {
        counts[0] = sA[511]; counts[1] = sB[511];
        rowstart_tail[0] = N_EDGES;
    }
}

// ---------- scan C: rowstart/dinv + mapA/mapB + packed worklists ------------
__global__ void k_scanC(const uint* __restrict__ degP, const uint* __restrict__ fAw,
                        const uint* __restrict__ fBw,
                        const int* __restrict__ boffD, const int* __restrict__ boffA,
                        const int* __restrict__ boffB,
                        int* __restrict__ rowstart, float* __restrict__ dinv,
                        int* __restrict__ mapA, int* __restrict__ mapB,
                        int4* __restrict__ listA4, int4* __restrict__ listB4) {
    __shared__ int sD[SCAN_B];
    __shared__ int sP[SCAN_B];
    int i = blockIdx.x * SCAN_B + threadIdx.x;
    int d = 0, a = 0, b = 0;
    if (i < N_NODES) {
        d = (degP[i >> 2] >> ((i & 3) * 8)) & 0xFF;
        a = getbit(fAw, i); b = getbit(fBw, i);
    }
    sD[threadIdx.x] = d; sP[threadIdx.x] = a | (b << 16);
    __syncthreads();
    for (int off = 1; off < SCAN_B; off <<= 1) {
        int tD = (threadIdx.x >= off) ? sD[threadIdx.x - off] : 0;
        int tP = (threadIdx.x >= off) ? sP[threadIdx.x - off] : 0;
        __syncthreads();
        sD[threadIdx.x] += tD; sP[threadIdx.x] += tP;
        __syncthreads();
    }
    if (i < N_NODES) {
        int exD = sD[threadIdx.x] - d + boffD[blockIdx.x];
        int incP = sP[threadIdx.x];
        int exA = (incP & 0xFFFF) - a + boffA[blockIdx.x];
        int exB = (incP >> 16) - b + boffB[blockIdx.x];
        rowstart[i] = exD;
        float dv = (d > 0) ? rsqrtf((float)d) : 0.0f;
        dinv[i] = dv;
        mapA[i] = a ? exA : -1;
        mapB[i] = b ? exB : -1;
        int4 ent = make_int4(exD, exD + d, __float_as_int(dv), 0);
        if (a) listA4[exA] = ent;
        if (b) listB4[exB] = ent;
    }
}

// ---------- conv: embs = bf16(emb * dinv[row]) (pre-scaled) -----------------
__global__ void k_conv(const float* __restrict__ emb, const float* __restrict__ dinv,
                       ushort* __restrict__ embs) {
    int c = blockIdx.x * blockDim.x + threadIdx.x;   // chunk of 4 floats
    if (c < N_NODES * 16) {
        int row = c >> 4;
        float4 v = ((const float4*)emb)[c];
        float dv = dinv[row];
        uint2 o;
        o.x = (uint)f2bf(v.x * dv) | ((uint)f2bf(v.y * dv) << 16);
        o.y = (uint)f2bf(v.z * dv) | ((uint)f2bf(v.w * dv) << 16);
        ((uint2*)embs)[c] = o;
    }
}

// ---------- masked scatter with packed-byte cursors -------------------------
__global__ void k_scatter(const int* __restrict__ src, const int* __restrict__ dst,
                          const uint* __restrict__ fBw, const int* __restrict__ rowstart,
                          uint* __restrict__ cur8, int* __restrict__ csr_src) {
    int t = blockIdx.x * blockDim.x + threadIdx.x;
    if (t < N_EDGES / 4) {
        int4 s = ((const int4*)src)[t];
        int4 d = ((const int4*)dst)[t];
        #define SCAT(dd, ss) \
            if (getbit(fBw, dd)) { \
                uint old = atomicAdd(&cur8[(dd) >> 2], 1u << (((dd) & 3) * 8)); \
                int off = (old >> (((dd) & 3) * 8)) & 0xFF; \
                csr_src[rowstart[dd] + off] = (ss); \
            }
        SCAT(d.x, s.x) SCAT(d.y, s.y) SCAT(d.z, s.z) SCAT(d.w, s.w)
        #undef SCAT
    }
}

// ---------- layer 1: embs(bf16, pre-scaled) -> x1c(bf16, x1*dinv[node]) -----
__global__ void k_prop1(const ushort* __restrict__ embs, const int4* __restrict__ listB4,
                        const int* __restrict__ counts, const int* __restrict__ csr_src,
                        ushort* __restrict__ x1c) {
    int lane = threadIdx.x & 63;
    int wv = (blockIdx.x * blockDim.x + threadIdx.x) >> 6;
    if (wv >= counts[1]) return;
    int4 nb = listB4[wv];
    int sub = lane >> 4, q = lane & 15;
    float4 acc = {0.f, 0.f, 0.f, 0.f};
    for (int i = nb.x + sub; i < nb.y; i += 4) {
        int s = csr_src[i];
        uint2 u = *(const uint2*)(embs + (size_t)s * DIM + q * 4);
        acc.x += bflo(u.x); acc.y += bfhi(u.x);
        acc.z += bflo(u.y); acc.w += bfhi(u.y);
    }
    for (int off = 16; off <= 32; off <<= 1) {
        acc.x += __shfl_xor(acc.x, off, 64);
        acc.y += __shfl_xor(acc.y, off, 64);
        acc.z += __shfl_xor(acc.z, off, 64);
        acc.w += __shfl_xor(acc.w, off, 64);
    }
    if (sub == 0) {
        float dv = __int_as_float(nb.z);
        float d2 = dv * dv;   // store x1*dinv[node] for next layer
        uint2 o;
        o.x = (uint)f2bf(acc.x * d2) | ((uint)f2bf(acc.y * d2) << 16);
        o.y = (uint)f2bf(acc.z * d2) | ((uint)f2bf(acc.w * d2) << 16);
        *(uint2*)(x1c + (size_t)wv * DIM + q * 4) = o;
    }
}

// ---------- layer 2: x1c -> x2c (bf16, x2*dinv[node]) -----------------------
__global__ void k_prop2(const ushort* __restrict__ x1c, const int* __restrict__ mapB,
                        const int4* __restrict__ listA4, const int* __restrict__ counts,
                        const int* __restrict__ csr_src, ushort* __restrict__ x2c) {
    int lane = threadIdx.x & 63;
    int wv = (blockIdx.x * blockDim.x + threadIdx.x) >> 6;
    if (wv >= counts[0]) return;
    int4 nb = listA4[wv];
    int sub = lane >> 4, q = lane & 15;
    float4 acc = {0.f, 0.f, 0.f, 0.f};
    for (int i = nb.x + sub; i < nb.y; i += 4) {
        int s = csr_src[i];
        int slot = mapB[s];
        uint2 u = *(const uint2*)(x1c + (size_t)slot * DIM + q * 4);
        acc.x += bflo(u.x); acc.y += bfhi(u.x);
        acc.z += bflo(u.y); acc.w += bfhi(u.y);
    }
    for (int off = 16; off <= 32; off <<= 1) {
        acc.x += __shfl_xor(acc.x, off, 64);
        acc.y += __shfl_xor(acc.y, off, 64);
        acc.z += __shfl_xor(acc.z, off, 64);
        acc.w += __shfl_xor(acc.w, off, 64);
    }
    if (sub == 0) {
        float dv = __int_as_float(nb.z);
        float d2 = dv * dv;
        uint2 o;
        o.x = (uint)f2bf(acc.x * d2) | ((uint)f2bf(acc.y * d2) << 16);
        o.y = (uint)f2bf(acc.z * d2) | ((uint)f2bf(acc.w * d2) << 16);
        *(uint2*)(x2c + (size_t)wv * DIM + q * 4) = o;
    }
}

// ---------- layer 3: x2c -> x3c (fp32 true values, 3*BATCH rows) ------------
__global__ void k_prop3(const ushort* __restrict__ x2c, const int* __restrict__ mapA,
                        const int* __restrict__ u, const int* __restrict__ p,
                        const int* __restrict__ n, const float* __restrict__ dinv,
                        const int* __restrict__ rowstart, const int* __restrict__ csr_src,
                        float* __restrict__ x3c) {
    int lane = threadIdx.x & 63;
    int wv = (blockIdx.x * blockDim.x + threadIdx.x) >> 6;
    if (wv >= 3 * BATCH) return;
    int t;
    if (wv < BATCH)          t = u[wv];
    else if (wv < 2 * BATCH) t = p[wv - BATCH];
    else                     t = n[wv - 2 * BATCH];
    int sub = lane >> 4, q = lane & 15;
    int b = rowstart[t], e = rowstart[t + 1];
    float4 acc = {0.f, 0.f, 0.f, 0.f};
    for (int i = b + sub; i < e; i += 4) {
        int s = csr_src[i];
        int slot = mapA[s];
        uint2 uu = *(const uint2*)(x2c + (size_t)slot * DIM + q * 4);
        acc.x += bflo(uu.x); acc.y += bfhi(uu.x);
        acc.z += bflo(uu.y); acc.w += bfhi(uu.y);
    }
    for (int off = 16; off <= 32; off <<= 1) {
        acc.x += __shfl_xor(acc.x, off, 64);
        acc.y += __shfl_xor(acc.y, off, 64);
        acc.z += __shfl_xor(acc.z, off, 64);
        acc.w += __shfl_xor(acc.w, off, 64);
    }
    if (sub == 0) {
        float dv = dinv[t];
        float4 o = {acc.x * dv, acc.y * dv, acc.z * dv, acc.w * dv};
        ((float4*)x3c)[(size_t)wv * 16 + q] = o;
    }
}

// ---------- final loss ------------------------------------------------------
__global__ void k_loss(const float* __restrict__ emb, const ushort* __restrict__ x1c,
                       const ushort* __restrict__ x2c, const float* __restrict__ x3c,
                       const int* __restrict__ mapA, const int* __restrict__ mapB,
                       const float* __restrict__ dinv,
                       const int* __restrict__ u, const int* __restrict__ p,
                       const int* __restrict__ n, float* __restrict__ out) {
    int lane = threadIdx.x & 63;
    int w = (blockIdx.x * blockDim.x + threadIdx.x) >> 6;
    if (w >= BATCH) return;
    int ui = u[w], pi = p[w], ni = n[w];
    float dvu = dinv[ui], dvp = dinv[pi], dvn = dinv[ni];
    float rdu = dvu > 0.f ? 1.f / dvu : 0.f;
    float rdp = dvp > 0.f ? 1.f / dvp : 0.f;
    float rdn = dvn > 0.f ? 1.f / dvn : 0.f;
    float ue = emb[(size_t)ui * DIM + lane];
    float pe = emb[(size_t)pi * DIM + lane];
    float ne = emb[(size_t)ni * DIM + lane];
    float u1 = __uint_as_float((uint)x1c[(size_t)mapB[ui] * DIM + lane] << 16) * rdu;
    float p1 = __uint_as_float((uint)x1c[(size_t)mapB[pi] * DIM + lane] << 16) * rdp;
    float n1 = __uint_as_float((uint)x1c[(size_t)mapB[ni] * DIM + lane] << 16) * rdn;
    float u2 = __uint_as_float((uint)x2c[(size_t)mapA[ui] * DIM + lane] << 16) * rdu;
    float p2 = __uint_as_float((uint)x2c[(size_t)mapA[pi] * DIM + lane] << 16) * rdp;
    float n2 = __uint_as_float((uint)x2c[(size_t)mapA[ni] * DIM + lane] << 16) * rdn;
    float uall = 0.25f * (ue + u1 + u2 + x3c[(size_t)w * DIM + lane]);
    float pall = 0.25f * (pe + p1 + p2 + x3c[(size_t)(BATCH + w) * DIM + lane]);
    float nall = 0.25f * (ne + n1 + n2 + x3c[(size_t)(2 * BATCH + w) * DIM + lane]);
    float pos = uall * pall;
    float neg = uall * nall;
    float sq  = ue * ue + pe * pe + ne * ne;
    for (int off = 32; off; off >>= 1) {
        pos += __shfl_xor(pos, off, 64);
        neg += __shfl_xor(neg, off, 64);
        sq  += __shfl_xor(sq,  off, 64);
    }
    if (lane == 0) {
        float z = neg - pos;
        float sp = fmaxf(z, 0.0f) + log1pf(expf(-fabsf(z)));
        float contrib = sp * (1.0f / BATCH) + 1e-4f * 0.5f * sq * (1.0f / BATCH);
        atomicAdd(out, contrib);
    }
}

extern "C" void kernel_launch(void* const* d_in, const int* in_sizes, int n_in,
                              void* d_out, int out_size, void* d_ws, size_t ws_size,
                              hipStream_t stream) {
    const float* emb  = (const float*)d_in[0];
    const int*   edge = (const int*)d_in[1];
    const int*   src  = edge;
    const int*   dst  = edge + N_EDGES;
    const int*   uidx = (const int*)d_in[2];
    const int*   pidx = (const int*)d_in[3];
    const int*   nidx = (const int*)d_in[4];
    float* out = (float*)d_out;

    // ---- workspace layout (~158 MB) ----
    char* w = (char*)d_ws;
    ushort* embs    = (ushort*)w;                w += (size_t)N_NODES * DIM * 2;   // 64 MB
    ushort* x1c     = (ushort*)w;                w += (size_t)X1C_CAP * DIM * 2;   // 44.8 MB
    ushort* x2c     = (ushort*)w;                w += (size_t)LA_CAP * DIM * 2;    // 19.2 MB
    float*  x3c     = (float*)w;                 w += (size_t)3 * BATCH * DIM * 4; // 3.1 MB
    float*  dinv    = (float*)w;                 w += (size_t)N_NODES * 4;
    int*    rowstart= (int*)w;                   w += (size_t)(N_NODES + 4) * 4;
    int*    csr_src = (int*)w;                   w += (size_t)N_EDGES * 4;
    int*    mapA    = (int*)w;                   w += (size_t)N_NODES * 4;
    int*    mapB    = (int*)w;                   w += (size_t)N_NODES * 4;
    int4*   listA4  = (int4*)w;                  w += (size_t)LA_CAP * 16;
    int4*   listB4  = (int4*)w;                  w += (size_t)X1C_CAP * 16;
    // --- zeroed region (single memset): degP, cur8, 3 bitmasks ---
    char*   zbase   = w;
    uint*   degP    = (uint*)w;                  w += (size_t)NPACK * 4;           // 500 KB
    uint*   cur8    = (uint*)w;                  w += (size_t)NPACK * 4;           // 500 KB
    uint*   f3w     = (uint*)w;                  w += (size_t)NMASKW * 4;
    uint*   fAw     = (uint*)w;                  w += (size_t)NMASKW * 4;
    uint*   fBw     = (uint*)w;                  w += (size_t)NMASKW * 4;
    size_t  zbytes  = (size_t)(w - zbase);
    int*    bsumD   = (int*)w;                   w += (size_t)NBLK * 4;
    int*    boffD   = (int*)w;                   w += (size_t)NBLK * 4;
    int*    bsumP   = (int*)w;                   w += (size_t)NBLK * 4;
    int*    boffA   = (int*)w;                   w += (size_t)NBLK * 4;
    int*    boffB   = (int*)w;                   w += (size_t)NBLK * 4;
    int*    counts  = (int*)w;                   w += 16;   // [0]=|fA|, [1]=|fB|

    hipMemsetAsync(zbase, 0, zbytes, stream);
    hipMemsetAsync(out, 0, 4, stream);

    // frontier + degree (2 edge passes; bit flags + packed byte histogram)
    k_mark<<<(3 * BATCH + 255) / 256, 256, 0, stream>>>(uidx, pidx, nidx, f3w, fAw, fBw);
    k_degexp<<<(N_EDGES / 4 + 255) / 256, 256, 0, stream>>>(src, dst, degP, f3w, fAw);
    k_expand<<<(N_EDGES / 4 + 255) / 256, 256, 0, stream>>>(src, dst, fAw, fBw);

    // fused scan trio: CSR offsets + dinv + compact maps + packed worklists
    k_scanA<<<NBLK, SCAN_B, 0, stream>>>(degP, fAw, fBw, bsumD, bsumP);
    k_scanB<<<1, 512, 0, stream>>>(bsumD, bsumP, boffD, boffA, boffB, counts,
                                   rowstart + N_NODES);
    k_scanC<<<NBLK, SCAN_B, 0, stream>>>(degP, fAw, fBw, boffD, boffA, boffB,
                                         rowstart, dinv, mapA, mapB, listA4, listB4);

    // bf16 pre-scaled staging of emb
    k_conv<<<(N_NODES * 16 + 255) / 256, 256, 0, stream>>>(emb, dinv, embs);

    // masked CSR fill (packed byte cursors)
    k_scatter<<<(N_EDGES / 4 + 255) / 256, 256, 0, stream>>>(src, dst, fBw, rowstart,
                                                             cur8, csr_src);

    // sparse propagation
    const int PT = 256;
    k_prop1<<<((size_t)X1C_CAP * 64 + PT - 1) / PT, PT, 0, stream>>>(
        embs, listB4, counts, csr_src, x1c);
    k_prop2<<<((size_t)LA_CAP * 64 + PT - 1) / PT, PT, 0, stream>>>(
        x1c, mapB, listA4, counts, csr_src, x2c);
    k_prop3<<<(3 * BATCH * 64 + PT - 1) / PT, PT, 0, stream>>>(
        x2c, mapA, uidx, pidx, nidx, dinv, rowstart, csr_src, x3c);

    k_loss<<<(BATCH * 64 + 255) / 256, 256, 0, stream>>>(
        emb, x1c, x2c, x3c, mapA, mapB, dinv, uidx, pidx, nidx, out);
}

// Round 9
// 500.436 us; speedup vs baseline: 1.1204x; 1.1204x over previous
//
#include <hip/hip_runtime.h>
#include <cstdint>
#include <cstddef>

#define N_USERS   100000
#define N_NODES   500000
#define DIM       64
#define N_EDGES   2000000
#define BATCH     4096
#define SCAN_B    1024
#define NBLK      ((N_NODES + SCAN_B - 1) / SCAN_B)   // 489
#define X1C_CAP   350000   // |fB| ~230k measured-safe
#define LA_CAP    150000   // |fA| ~60k expected

typedef unsigned char uchar;
typedef unsigned short ushort;
typedef unsigned int uint;

__device__ __forceinline__ ushort f2bf(float f) {
    uint u = __float_as_uint(f);
    uint r = u + 0x7FFFu + ((u >> 16) & 1u);
    return (ushort)(r >> 16);
}
__device__ __forceinline__ float bflo(uint u) { return __uint_as_float(u << 16); }
__device__ __forceinline__ float bfhi(uint u) { return __uint_as_float(u & 0xFFFF0000u); }

// ---------- mark batch indices into three byte flags ------------------------
__global__ void k_mark(const int* __restrict__ u, const int* __restrict__ p,
                       const int* __restrict__ n, uchar* __restrict__ f3,
                       uchar* __restrict__ fA, uchar* __restrict__ fB) {
    int i = blockIdx.x * blockDim.x + threadIdx.x;
    if (i >= 3 * BATCH) return;
    int idx;
    if (i < BATCH)          idx = u[i];
    else if (i < 2 * BATCH) idx = p[i - BATCH];
    else                    idx = n[i - 2 * BATCH];
    f3[idx] = 1; fA[idx] = 1; fB[idx] = 1;
}

// ---------- fused: degree histogram + expand f3 -> fA (8 edges/thread) ------
__global__ void k_degexp(const int* __restrict__ src, const int* __restrict__ dst,
                         int* __restrict__ deg, const uchar* __restrict__ f3,
                         uchar* __restrict__ fA) {
    int t = blockIdx.x * blockDim.x + threadIdx.x;
    if (t < N_EDGES / 8) {
        int4 s0 = ((const int4*)src)[2 * t];
        int4 s1 = ((const int4*)src)[2 * t + 1];
        int4 d0 = ((const int4*)dst)[2 * t];
        int4 d1 = ((const int4*)dst)[2 * t + 1];
        atomicAdd(&deg[d0.x], 1); atomicAdd(&deg[d0.y], 1);
        atomicAdd(&deg[d0.z], 1); atomicAdd(&deg[d0.w], 1);
        atomicAdd(&deg[d1.x], 1); atomicAdd(&deg[d1.y], 1);
        atomicAdd(&deg[d1.z], 1); atomicAdd(&deg[d1.w], 1);
        if (f3[d0.x] && !fA[s0.x]) fA[s0.x] = 1;
        if (f3[d0.y] && !fA[s0.y]) fA[s0.y] = 1;
        if (f3[d0.z] && !fA[s0.z]) fA[s0.z] = 1;
        if (f3[d0.w] && !fA[s0.w]) fA[s0.w] = 1;
        if (f3[d1.x] && !fA[s1.x]) fA[s1.x] = 1;
        if (f3[d1.y] && !fA[s1.y]) fA[s1.y] = 1;
        if (f3[d1.z] && !fA[s1.z]) fA[s1.z] = 1;
        if (f3[d1.w] && !fA[s1.w]) fA[s1.w] = 1;
    }
}

// ---------- expand fA -> fB (dedup writes, 8 edges/thread) ------------------
__global__ void k_expand(const int* __restrict__ src, const int* __restrict__ dst,
                         const uchar* __restrict__ fin, uchar* __restrict__ fout) {
    int t = blockIdx.x * blockDim.x + threadIdx.x;
    if (t < N_EDGES / 8) {
        int4 s0 = ((const int4*)src)[2 * t];
        int4 s1 = ((const int4*)src)[2 * t + 1];
        int4 d0 = ((const int4*)dst)[2 * t];
        int4 d1 = ((const int4*)dst)[2 * t + 1];
        if (fin[d0.x] && !fout[s0.x]) fout[s0.x] = 1;
        if (fin[d0.y] && !fout[s0.y]) fout[s0.y] = 1;
        if (fin[d0.z] && !fout[s0.z]) fout[s0.z] = 1;
        if (fin[d0.w] && !fout[s0.w]) fout[s0.w] = 1;
        if (fin[d1.x] && !fout[s1.x]) fout[s1.x] = 1;
        if (fin[d1.y] && !fout[s1.y]) fout[s1.y] = 1;
        if (fin[d1.z] && !fout[s1.z]) fout[s1.z] = 1;
        if (fin[d1.w] && !fout[s1.w]) fout[s1.w] = 1;
    }
}

// ---------- scan A: per-block sums of deg (int) and fA|fB (packed) ----------
__global__ void k_scanA(const int* __restrict__ deg, const uchar* __restrict__ fA,
                        const uchar* __restrict__ fB, int* __restrict__ bsumD,
                        int* __restrict__ bsumP) {
    __shared__ int sD[SCAN_B];
    __shared__ int sP[SCAN_B];
    int i = blockIdx.x * SCAN_B + threadIdx.x;
    int d = 0, pk = 0;
    if (i < N_NODES) { d = deg[i]; pk = (int)fA[i] | ((int)fB[i] << 16); }
    sD[threadIdx.x] = d; sP[threadIdx.x] = pk;
    __syncthreads();
    for (int off = SCAN_B / 2; off; off >>= 1) {
        if (threadIdx.x < off) {
            sD[threadIdx.x] += sD[threadIdx.x + off];
            sP[threadIdx.x] += sP[threadIdx.x + off];
        }
        __syncthreads();
    }
    if (threadIdx.x == 0) { bsumD[blockIdx.x] = sD[0]; bsumP[blockIdx.x] = sP[0]; }
}

// ---------- scan B: exclusive scans of block sums ---------------------------
__global__ void k_scanB(const int* __restrict__ bsumD, const int* __restrict__ bsumP,
                        int* __restrict__ boffD, int* __restrict__ boffA,
                        int* __restrict__ boffB, int* __restrict__ counts) {
    __shared__ int sD[512];
    __shared__ int sA[512];
    __shared__ int sB[512];
    int d = (threadIdx.x < NBLK) ? bsumD[threadIdx.x] : 0;
    int p = (threadIdx.x < NBLK) ? bsumP[threadIdx.x] : 0;
    int a = p & 0xFFFF, b = p >> 16;
    sD[threadIdx.x] = d; sA[threadIdx.x] = a; sB[threadIdx.x] = b;
    __syncthreads();
    for (int off = 1; off < 512; off <<= 1) {
        int tD = (threadIdx.x >= off) ? sD[threadIdx.x - off] : 0;
        int tA = (threadIdx.x >= off) ? sA[threadIdx.x - off] : 0;
        int tB = (threadIdx.x >= off) ? sB[threadIdx.x - off] : 0;
        __syncthreads();
        sD[threadIdx.x] += tD; sA[threadIdx.x] += tA; sB[threadIdx.x] += tB;
        __syncthreads();
    }
    if (threadIdx.x < NBLK) {
        boffD[threadIdx.x] = sD[threadIdx.x] - d;
        boffA[threadIdx.x] = sA[threadIdx.x] - a;
        boffB[threadIdx.x] = sB[threadIdx.x] - b;
    }
    if (threadIdx.x == 511) { counts[0] = sA[511]; counts[1] = sB[511]; }
}

// ---------- scan C: rowstart/dinv + mapA/mapB + packed worklists ------------
__global__ void k_scanC(const int* __restrict__ deg, const uchar* __restrict__ fA,
                        const uchar* __restrict__ fB,
                        const int* __restrict__ boffD, const int* __restrict__ boffA,
                        const int* __restrict__ boffB,
                        int* __restrict__ rowstart, float* __restrict__ dinv,
                        int* __restrict__ mapA, int* __restrict__ mapB,
                        int4* __restrict__ listA4, int4* __restrict__ listB4) {
    __shared__ int sD[SCAN_B];
    __shared__ int sP[SCAN_B];
    int i = blockIdx.x * SCAN_B + threadIdx.x;
    int d = 0, a = 0, b = 0;
    if (i < N_NODES) { d = deg[i]; a = (int)fA[i]; b = (int)fB[i]; }
    sD[threadIdx.x] = d; sP[threadIdx.x] = a | (b << 16);
    __syncthreads();
    for (int off = 1; off < SCAN_B; off <<= 1) {
        int tD = (threadIdx.x >= off) ? sD[threadIdx.x - off] : 0;
        int tP = (threadIdx.x >= off) ? sP[threadIdx.x - off] : 0;
        __syncthreads();
        sD[threadIdx.x] += tD; sP[threadIdx.x] += tP;
        __syncthreads();
    }
    if (i < N_NODES) {
        int exD = sD[threadIdx.x] - d + boffD[blockIdx.x];
        int incP = sP[threadIdx.x];
        int exA = (incP & 0xFFFF) - a + boffA[blockIdx.x];
        int exB = (incP >> 16) - b + boffB[blockIdx.x];
        rowstart[i] = exD;
        float dv = (d > 0) ? rsqrtf((float)d) : 0.0f;
        dinv[i] = dv;
        mapA[i] = a ? exA : -1;
        mapB[i] = b ? exB : -1;
        int4 ent = make_int4(exD, exD + d, __float_as_int(dv), 0);
        if (a) listA4[exA] = ent;
        if (b) listB4[exB] = ent;
    }
}

// ---------- conv: embs = bf16(emb * dinv[row]) (pre-scaled) -----------------
__global__ void k_conv(const float* __restrict__ emb, const float* __restrict__ dinv,
                       ushort* __restrict__ embs) {
    int c = blockIdx.x * blockDim.x + threadIdx.x;   // chunk of 4 floats
    if (c < N_NODES * 16) {
        int row = c >> 4;
        float4 v = ((const float4*)emb)[c];
        float dv = dinv[row];
        uint2 o;
        o.x = (uint)f2bf(v.x * dv) | ((uint)f2bf(v.y * dv) << 16);
        o.y = (uint)f2bf(v.z * dv) | ((uint)f2bf(v.w * dv) << 16);
        ((uint2*)embs)[c] = o;
    }
}

// ---------- masked scatter: bump rowstart in place (8 edges/thread) ---------
__global__ void k_scatter(const int* __restrict__ src, const int* __restrict__ dst,
                          const uchar* __restrict__ fB, int* __restrict__ rowstart,
                          int* __restrict__ csr_src) {
    int t = blockIdx.x * blockDim.x + threadIdx.x;
    if (t < N_EDGES / 8) {
        int4 s0 = ((const int4*)src)[2 * t];
        int4 s1 = ((const int4*)src)[2 * t + 1];
        int4 d0 = ((const int4*)dst)[2 * t];
        int4 d1 = ((const int4*)dst)[2 * t + 1];
        if (fB[d0.x]) csr_src[atomicAdd(&rowstart[d0.x], 1)] = s0.x;
        if (fB[d0.y]) csr_src[atomicAdd(&rowstart[d0.y], 1)] = s0.y;
        if (fB[d0.z]) csr_src[atomicAdd(&rowstart[d0.z], 1)] = s0.z;
        if (fB[d0.w]) csr_src[atomicAdd(&rowstart[d0.w], 1)] = s0.w;
        if (fB[d1.x]) csr_src[atomicAdd(&rowstart[d1.x], 1)] = s1.x;
        if (fB[d1.y]) csr_src[atomicAdd(&rowstart[d1.y], 1)] = s1.y;
        if (fB[d1.z]) csr_src[atomicAdd(&rowstart[d1.z], 1)] = s1.z;
        if (fB[d1.w]) csr_src[atomicAdd(&rowstart[d1.w], 1)] = s1.w;
    }
}

// ---------- layer 1: embs(bf16, pre-scaled) -> x1c(bf16, x1*dinv[node]) -----
__global__ void k_prop1(const ushort* __restrict__ embs, const int4* __restrict__ listB4,
                        const int* __restrict__ counts, const int* __restrict__ csr_src,
                        ushort* __restrict__ x1c) {
    int lane = threadIdx.x & 63;
    int wv = (blockIdx.x * blockDim.x + threadIdx.x) >> 6;
    if (wv >= counts[1]) return;
    int4 nb = listB4[wv];
    int sub = lane >> 4, q = lane & 15;
    float4 acc = {0.f, 0.f, 0.f, 0.f};
    for (int i = nb.x + sub; i < nb.y; i += 4) {
        int s = csr_src[i];
        uint2 u = *(const uint2*)(embs + (size_t)s * DIM + q * 4);
        acc.x += bflo(u.x); acc.y += bfhi(u.x);
        acc.z += bflo(u.y); acc.w += bfhi(u.y);
    }
    for (int off = 16; off <= 32; off <<= 1) {
        acc.x += __shfl_xor(acc.x, off, 64);
        acc.y += __shfl_xor(acc.y, off, 64);
        acc.z += __shfl_xor(acc.z, off, 64);
        acc.w += __shfl_xor(acc.w, off, 64);
    }
    if (sub == 0) {
        float dv = __int_as_float(nb.z);
        float d2 = dv * dv;   // store x1*dinv[node] for next layer
        uint2 o;
        o.x = (uint)f2bf(acc.x * d2) | ((uint)f2bf(acc.y * d2) << 16);
        o.y = (uint)f2bf(acc.z * d2) | ((uint)f2bf(acc.w * d2) << 16);
        *(uint2*)(x1c + (size_t)wv * DIM + q * 4) = o;
    }
}

// ---------- layer 2: x1c -> x2c (bf16, x2*dinv[node]) -----------------------
__global__ void k_prop2(const ushort* __restrict__ x1c, const int* __restrict__ mapB,
                        const int4* __restrict__ listA4, const int* __restrict__ counts,
                        const int* __restrict__ csr_src, ushort* __restrict__ x2c) {
    int lane = threadIdx.x & 63;
    int wv = (blockIdx.x * blockDim.x + threadIdx.x) >> 6;
    if (wv >= counts[0]) return;
    int4 nb = listA4[wv];
    int sub = lane >> 4, q = lane & 15;
    float4 acc = {0.f, 0.f, 0.f, 0.f};
    for (int i = nb.x + sub; i < nb.y; i += 4) {
        int s = csr_src[i];
        int slot = mapB[s];
        uint2 u = *(const uint2*)(x1c + (size_t)slot * DIM + q * 4);
        acc.x += bflo(u.x); acc.y += bfhi(u.x);
        acc.z += bflo(u.y); acc.w += bfhi(u.y);
    }
    for (int off = 16; off <= 32; off <<= 1) {
        acc.x += __shfl_xor(acc.x, off, 64);
        acc.y += __shfl_xor(acc.y, off, 64);
        acc.z += __shfl_xor(acc.z, off, 64);
        acc.w += __shfl_xor(acc.w, off, 64);
    }
    if (sub == 0) {
        float dv = __int_as_float(nb.z);
        float d2 = dv * dv;
        uint2 o;
        o.x = (uint)f2bf(acc.x * d2) | ((uint)f2bf(acc.y * d2) << 16);
        o.y = (uint)f2bf(acc.z * d2) | ((uint)f2bf(acc.w * d2) << 16);
        *(uint2*)(x2c + (size_t)wv * DIM + q * 4) = o;
    }
}

// ---------- fused layer 3 + loss: wave per batch item -----------------------
__device__ __forceinline__ float x3_row(const ushort* __restrict__ x2c,
                                        const int* __restrict__ mapA,
                                        const int* __restrict__ csr_src,
                                        const int4* __restrict__ listB4,
                                        const int* __restrict__ mapB,
                                        int t, int lane) {
    int4 nb = listB4[mapB[t]];
    float acc = 0.f;
    for (int i = nb.x; i < nb.y; ++i) {
        int s = csr_src[i];
        int slot = mapA[s];
        acc += __uint_as_float((uint)x2c[(size_t)slot * DIM + lane] << 16);
    }
    return acc * __int_as_float(nb.z);
}

__global__ void k_loss(const float* __restrict__ emb, const ushort* __restrict__ x1c,
                       const ushort* __restrict__ x2c,
                       const int* __restrict__ mapA, const int* __restrict__ mapB,
                       const int4* __restrict__ listB4, const int* __restrict__ csr_src,
                       const float* __restrict__ dinv,
                       const int* __restrict__ u, const int* __restrict__ p,
                       const int* __restrict__ n, float* __restrict__ out) {
    int lane = threadIdx.x & 63;
    int w = (blockIdx.x * blockDim.x + threadIdx.x) >> 6;
    if (w >= BATCH) return;
    int ui = u[w], pi = p[w], ni = n[w];
    float dvu = dinv[ui], dvp = dinv[pi], dvn = dinv[ni];
    float rdu = dvu > 0.f ? 1.f / dvu : 0.f;
    float rdp = dvp > 0.f ? 1.f / dvp : 0.f;
    float rdn = dvn > 0.f ? 1.f / dvn : 0.f;
    float ue = emb[(size_t)ui * DIM + lane];
    float pe = emb[(size_t)pi * DIM + lane];
    float ne = emb[(size_t)ni * DIM + lane];
    float u1 = __uint_as_float((uint)x1c[(size_t)mapB[ui] * DIM + lane] << 16) * rdu;
    float p1 = __uint_as_float((uint)x1c[(size_t)mapB[pi] * DIM + lane] << 16) * rdp;
    float n1 = __uint_as_float((uint)x1c[(size_t)mapB[ni] * DIM + lane] << 16) * rdn;
    float u2 = __uint_as_float((uint)x2c[(size_t)mapA[ui] * DIM + lane] << 16) * rdu;
    float p2 = __uint_as_float((uint)x2c[(size_t)mapA[pi] * DIM + lane] << 16) * rdp;
    float n2 = __uint_as_float((uint)x2c[(size_t)mapA[ni] * DIM + lane] << 16) * rdn;
    float u3 = x3_row(x2c, mapA, csr_src, listB4, mapB, ui, lane);
    float p3 = x3_row(x2c, mapA, csr_src, listB4, mapB, pi, lane);
    float n3 = x3_row(x2c, mapA, csr_src, listB4, mapB, ni, lane);
    float uall = 0.25f * (ue + u1 + u2 + u3);
    float pall = 0.25f * (pe + p1 + p2 + p3);
    float nall = 0.25f * (ne + n1 + n2 + n3);
    float pos = uall * pall;
    float neg = uall * nall;
    float sq  = ue * ue + pe * pe + ne * ne;
    for (int off = 32; off; off >>= 1) {
        pos += __shfl_xor(pos, off, 64);
        neg += __shfl_xor(neg, off, 64);
        sq  += __shfl_xor(sq,  off, 64);
    }
    if (lane == 0) {
        float z = neg - pos;
        float sp = fmaxf(z, 0.0f) + log1pf(expf(-fabsf(z)));
        float contrib = sp * (1.0f / BATCH) + 1e-4f * 0.5f * sq * (1.0f / BATCH);
        atomicAdd(out, contrib);
    }
}

extern "C" void kernel_launch(void* const* d_in, const int* in_sizes, int n_in,
                              void* d_out, int out_size, void* d_ws, size_t ws_size,
                              hipStream_t stream) {
    const float* emb  = (const float*)d_in[0];
    const int*   edge = (const int*)d_in[1];
    const int*   src  = edge;
    const int*   dst  = edge + N_EDGES;
    const int*   uidx = (const int*)d_in[2];
    const int*   pidx = (const int*)d_in[3];
    const int*   nidx = (const int*)d_in[4];
    float* out = (float*)d_out;

    // ---- workspace layout (~155 MB) ----
    char* w = (char*)d_ws;
    ushort* embs    = (ushort*)w;                w += (size_t)N_NODES * DIM * 2;   // 64 MB
    ushort* x1c     = (ushort*)w;                w += (size_t)X1C_CAP * DIM * 2;   // 44.8 MB
    ushort* x2c     = (ushort*)w;                w += (size_t)LA_CAP * DIM * 2;    // 19.2 MB
    float*  dinv    = (float*)w;                 w += (size_t)N_NODES * 4;
    int*    rowstart= (int*)w;                   w += (size_t)N_NODES * 4;
    int*    csr_src = (int*)w;                   w += (size_t)N_EDGES * 4;
    int*    mapA    = (int*)w;                   w += (size_t)N_NODES * 4;
    int*    mapB    = (int*)w;                   w += (size_t)N_NODES * 4;
    int4*   listA4  = (int4*)w;                  w += (size_t)LA_CAP * 16;
    int4*   listB4  = (int4*)w;                  w += (size_t)X1C_CAP * 16;
    // --- zeroed region (single memset): deg + flags ---
    char*   zbase   = w;
    int*    deg     = (int*)w;                   w += (size_t)N_NODES * 4;         // 2 MB
    uchar*  flags   = (uchar*)w;                 w += (size_t)3 * N_NODES;         // 1.5 MB
    uchar*  f3 = flags;
    uchar*  fA = flags + N_NODES;
    uchar*  fB = flags + 2 * N_NODES;
    size_t  zbytes  = (size_t)(w - zbase);
    int*    bsumD   = (int*)w;                   w += (size_t)NBLK * 4;
    int*    boffD   = (int*)w;                   w += (size_t)NBLK * 4;
    int*    bsumP   = (int*)w;                   w += (size_t)NBLK * 4;
    int*    boffA   = (int*)w;                   w += (size_t)NBLK * 4;
    int*    boffB   = (int*)w;                   w += (size_t)NBLK * 4;
    int*    counts  = (int*)w;                   w += 16;   // [0]=|fA|, [1]=|fB|

    hipMemsetAsync(zbase, 0, zbytes, stream);
    hipMemsetAsync(out, 0, 4, stream);

    // frontier + degree (2 edge passes; 8 edges/thread for MLP)
    k_mark<<<(3 * BATCH + 255) / 256, 256, 0, stream>>>(uidx, pidx, nidx, f3, fA, fB);
    k_degexp<<<(N_EDGES / 8 + 255) / 256, 256, 0, stream>>>(src, dst, deg, f3, fA);
    k_expand<<<(N_EDGES / 8 + 255) / 256, 256, 0, stream>>>(src, dst, fA, fB);

    // fused scan trio: CSR offsets + dinv + compact maps + packed worklists
    k_scanA<<<NBLK, SCAN_B, 0, stream>>>(deg, fA, fB, bsumD, bsumP);
    k_scanB<<<1, 512, 0, stream>>>(bsumD, bsumP, boffD, boffA, boffB, counts);
    k_scanC<<<NBLK, SCAN_B, 0, stream>>>(deg, fA, fB, boffD, boffA, boffB,
                                         rowstart, dinv, mapA, mapB, listA4, listB4);

    // bf16 pre-scaled staging of emb
    k_conv<<<(N_NODES * 16 + 255) / 256, 256, 0, stream>>>(emb, dinv, embs);

    // masked CSR fill (bumps rowstart; worklists hold pristine [start,end])
    k_scatter<<<(N_EDGES / 8 + 255) / 256, 256, 0, stream>>>(src, dst, fB, rowstart,
                                                             csr_src);

    // sparse propagation
    const int PT = 256;
    k_prop1<<<((size_t)X1C_CAP * 64 + PT - 1) / PT, PT, 0, stream>>>(
        embs, listB4, counts, csr_src, x1c);
    k_prop2<<<((size_t)LA_CAP * 64 + PT - 1) / PT, PT, 0, stream>>>(
        x1c, mapB, listA4, counts, csr_src, x2c);

    // fused layer-3 + loss
    k_loss<<<(BATCH * 64 + 255) / 256, 256, 0, stream>>>(
        emb, x1c, x2c, mapA, mapB, listB4, csr_src, dinv, uidx, pidx, nidx, out);
}